// Round 18
// baseline (940.021 us; speedup 1.0000x reference)
//
#include <hip/hip_runtime.h>
#include <hip/hip_bf16.h>
#include <stdint.h>

// ChebNet: fp16 Chebyshev T-storage, 10-slot flat concat buffer, single full-K
// f16 MFMA GEMM per conv layer, two-pass BN, fp16 MFMA head.
// R18: full revert to R15 (last known-good, 940us / absmax 0.0078125).
// Dbuf GEMM abandoned: R16/R17 both produced absmax~0.29 (wrong staged data;
// LDS-DMA drain guarantee does not hold for the cross-buffer schedule).

#define N_NODES 20000
#define N_EDGES 320000
#define FDIM_IN 128
#define DD1 256
#define DD2 128
#define DD3 64
#define K_CHEB 10
#define EPSBN 1e-5f
#define BN_B 512  // partial blocks for BN pass1
#define E_PAD (N_EDGES + 8 * N_NODES)  // padded-CSR capacity

typedef unsigned short u16;
typedef unsigned int u32;
typedef _Float16 half8 __attribute__((ext_vector_type(8)));
typedef __attribute__((ext_vector_type(4))) float floatx4;

__device__ __forceinline__ u16 f2h(float v) {
  _Float16 h = (_Float16)v;
  return *reinterpret_cast<u16*>(&h);
}

__device__ __forceinline__ void gld16(const void* g, void* l) {
  __builtin_amdgcn_global_load_lds((const __attribute__((address_space(1))) u32*)g,
                                   (__attribute__((address_space(3))) u32*)l, 16, 0, 0);
}

// ---------------- graph setup ----------------
__global__ void detect_idx_kernel(const void* ei, int* flag) {
  int t = threadIdx.x;
  const int* p = (const int*)ei;
  int v = p[2 * t + 1];
  unsigned long long b = __ballot(v == 0);
  if (t == 0) *flag = (b == ~0ULL) ? 1 : 0;
}

__device__ __forceinline__ int load_edge(const void* ei, int mode64, long long pos) {
  return mode64 ? (int)((const long long*)ei)[pos] : ((const int*)ei)[pos];
}

__global__ void deg_kernel(const void* ei, const int* __restrict__ flag, int* __restrict__ ideg) {
  int e = blockIdx.x * blockDim.x + threadIdx.x;
  if (e < N_EDGES) {
    int d = load_edge(ei, *flag, (long long)N_EDGES + e);
    atomicAdd(&ideg[d], 1);
  }
}

// dinv from REAL degree; idegP = degree padded up to multiple of 8
__global__ void dinv_kernel(const int* __restrict__ ideg, float* __restrict__ dinv,
                            int* __restrict__ idegP) {
  int n = blockIdx.x * blockDim.x + threadIdx.x;
  if (n < N_NODES) {
    int d = ideg[n];
    dinv[n] = d > 0 ? rsqrtf((float)d) : 0.f;
    idegP[n] = (d + 7) & ~7;
  }
}

__global__ __launch_bounds__(1024) void scan_kernel(const int* __restrict__ ideg, int* __restrict__ rowptr) {
  __shared__ int part[1024];
  int tid = threadIdx.x;
  const int CH = (N_NODES + 1023) / 1024;
  int base = tid * CH;
  int s = 0;
  for (int i = 0; i < CH; i++) { int idx = base + i; if (idx < N_NODES) s += ideg[idx]; }
  part[tid] = s;
  __syncthreads();
  for (int off = 1; off < 1024; off <<= 1) {
    int v = (tid >= off) ? part[tid - off] : 0;
    __syncthreads();
    part[tid] += v;
    __syncthreads();
  }
  int run = (tid == 0) ? 0 : part[tid - 1];
  for (int i = 0; i < CH; i++) { int idx = base + i; if (idx < N_NODES) { rowptr[idx] = run; run += ideg[idx]; } }
  if (tid == 1023) rowptr[N_NODES] = run;
}

__global__ void fill_csr_kernel(const void* ei, const int* __restrict__ flag,
                                const float* __restrict__ dinv, const int* __restrict__ rowptr,
                                int* __restrict__ cnt, int* __restrict__ col, float* __restrict__ wcsr) {
  int e = blockIdx.x * blockDim.x + threadIdx.x;
  if (e < N_EDGES) {
    int m = *flag;
    int s = load_edge(ei, m, e);
    int d = load_edge(ei, m, (long long)N_EDGES + e);
    int pos = rowptr[d] + atomicAdd(&cnt[d], 1);
    col[pos] = s;
    wcsr[pos] = -dinv[s] * dinv[d];
  }
}

// fill pad slots [beg+deg .. beg+degP) with col=self, w=0 (exact no-op adds)
__global__ void pad_csr_kernel(const int* __restrict__ ideg, const int* __restrict__ rowptr,
                               int* __restrict__ col, float* __restrict__ wcsr) {
  int n = blockIdx.x * blockDim.x + threadIdx.x;
  if (n < N_NODES) {
    int d = ideg[n];
    int beg = rowptr[n], end = rowptr[n + 1];
    for (int e = beg + d; e < end; e++) { col[e] = n; wcsr[e] = 0.f; }
  }
}

// ---------------- weight transpose-convert: W[KF][Nd] fp32 -> Wt[Nd][KF] fp16 ----------------
__global__ __launch_bounds__(256) void wt_kernel(const float* __restrict__ W, u16* __restrict__ Wt,
                                                 int KF, int Nd) {
  __shared__ float sm[32][36];
  int kf0 = blockIdx.x * 32, n0 = blockIdx.y * 32;
  int r = threadIdx.x >> 3, c4 = (threadIdx.x & 7) * 4;
  float4 v = *(const float4*)(W + (size_t)(kf0 + r) * Nd + n0 + c4);
  sm[r][c4 + 0] = v.x; sm[r][c4 + 1] = v.y; sm[r][c4 + 2] = v.z; sm[r][c4 + 3] = v.w;
  __syncthreads();
  int on = threadIdx.x >> 3, okf4 = (threadIdx.x & 7) * 4;
  ushort4 u;
  u.x = f2h(sm[okf4 + 0][on]);
  u.y = f2h(sm[okf4 + 1][on]);
  u.z = f2h(sm[okf4 + 2][on]);
  u.w = f2h(sm[okf4 + 3][on]);
  *(ushort4*)(Wt + (size_t)(n0 + on) * KF + kf0 + okf4) = u;
}

// ---------------- convert h fp32 -> fp16 into cat slot 0 (T0); row stride 10F ----------------
template <int F>
__global__ void convert_cat_kernel(const float* __restrict__ in, u16* __restrict__ cat) {
  constexpr int F8 = F / 8;
  int i = blockIdx.x * blockDim.x + threadIdx.x;  // over N*F8
  int n = i / F8, f8 = i % F8;
  const float4* p = (const float4*)(in + (size_t)n * F + f8 * 8);
  float4 a = p[0], b = p[1];
  half8 o;
  o[0] = (_Float16)a.x; o[1] = (_Float16)a.y; o[2] = (_Float16)a.z; o[3] = (_Float16)a.w;
  o[4] = (_Float16)b.x; o[5] = (_Float16)b.y; o[6] = (_Float16)b.z; o[7] = (_Float16)b.w;
  *(half8*)(cat + (size_t)n * (10 * F) + f8 * 8) = o;
}

// ---------------- L_hat, XCD-sliced, padded CSR, software-pipelined batches ----------------
// slot_out = scale * gather(slot_in) - slot_tx0. blockIdx%8 -> XCD role
// (feature-slice q x node group grp); slice data L2-resident. fp32 weights.
template <int F, bool HAS_TX0>
__global__ void lhat8_kernel(u16* __restrict__ cat,
                             const int* __restrict__ rowptr, const int* __restrict__ col,
                             const float* __restrict__ w, float scale,
                             int inOff, int tx0Off, int outOff) {
  constexpr int R = 10 * F;                  // cat row stride (halves)
  constexpr int SLICES = F / 64;             // 4 (F=256) or 2 (F=128)
  constexpr int NPG = N_NODES * SLICES / 8;  // 10000 (F=256) / 5000 (F=128)
  int xcd = blockIdx.x & 7;
  int lb = blockIdx.x >> 3;
  int q = xcd % SLICES;
  int grp = xcd / SLICES;
  int node0 = grp * NPG;
  int node = node0 + lb * 32 + (threadIdx.x >> 3);
  if (node >= node0 + NPG || node >= N_NODES) return;
  int ln8 = q * 64 + (threadIdx.x & 7) * 8;  // element offset within a slot
  int beg = rowptr[node], end = rowptr[node + 1];  // multiple of 8 (>=8)
  float acc[8] = {0.f, 0.f, 0.f, 0.f, 0.f, 0.f, 0.f, 0.f};

  // prologue: load batch 0
  float wv[8];
  half8 v[8];
#pragma unroll
  for (int j = 0; j < 8; j++) {
    int c = col[beg + j];
    wv[j] = w[beg + j];
    v[j] = *(const half8*)(cat + (size_t)c * R + inOff + ln8);
  }
  for (int e = beg + 8; e < end; e += 8) {
    float w2[8];
    half8 v2[8];
#pragma unroll
    for (int j = 0; j < 8; j++) {
      int c = col[e + j];
      w2[j] = w[e + j];
      v2[j] = *(const half8*)(cat + (size_t)c * R + inOff + ln8);
    }
#pragma unroll
    for (int j = 0; j < 8; j++)
#pragma unroll
      for (int i = 0; i < 8; i++) acc[i] += wv[j] * (float)v[j][i];
#pragma unroll
    for (int j = 0; j < 8; j++) { wv[j] = w2[j]; v[j] = v2[j]; }
  }
#pragma unroll
  for (int j = 0; j < 8; j++)
#pragma unroll
    for (int i = 0; i < 8; i++) acc[i] += wv[j] * (float)v[j][i];

  float r[8];
#pragma unroll
  for (int i = 0; i < 8; i++) r[i] = scale * acc[i];
  if (HAS_TX0) {
    half8 t = *(const half8*)(cat + (size_t)node * R + tx0Off + ln8);
#pragma unroll
    for (int i = 0; i < 8; i++) r[i] -= (float)t[i];
  }
  half8 o;
#pragma unroll
  for (int i = 0; i < 8; i++) o[i] = (_Float16)r[i];
  *(half8*)(cat + (size_t)node * R + outOff + ln8) = o;
}

// ---------------- f16 MFMA GEMM: C[M][ldC] = A[M][ldA]f16(Kc cols) @ B[Nc][ldB]^T ----------------
// Tile 64(M) x 64(N) x 64(K); 4 waves (2x2), each 32x32. 1-D grid with
// XCD-chunked swizzle. Single-buffered staging (known-good): stage -> barrier
// -> compute, barrier protecting reads before overwrite. Optional fp16 copy.
__global__ __launch_bounds__(256) void gemm_cat_kernel(
    const u16* __restrict__ A, int ldA, const u16* __restrict__ B, int ldB, int kBase,
    int Kc, float* __restrict__ C, int ldC, int Nc, const float* __restrict__ bias, int M,
    int NX, int NY, int accFlag, int reluFlag, u16* __restrict__ dst16, int ld16) {
  __shared__ __align__(16) u16 As[64 * 64];    // 8 KB
  __shared__ __align__(16) u16 Bs[64 * 64];    // 8 KB
  int pid = blockIdx.x;
  int g8 = 8 * NY;
  int a8 = pid / g8, rem = pid % g8;
  int by = rem >> 3;
  int bx = a8 * 8 + (rem & 7);
  if (bx >= NX) return;
  int tid = threadIdx.x;
  int lane = tid & 63, wave = tid >> 6;
  int wr = wave >> 1, wc = wave & 1;
  int l15 = lane & 15, l16 = lane >> 4;
  int m0 = bx * 64, n0 = by * 64;
  floatx4 acc[2][2];
#pragma unroll
  for (int m = 0; m < 2; m++)
#pragma unroll
    for (int n = 0; n < 2; n++) acc[m][n] = (floatx4){0.f, 0.f, 0.f, 0.f};

  int subrow = lane >> 3;          // 0..7
  int bcol = (lane & 7) * 16;      // byte col within 128B row

  for (int k0 = 0; k0 < Kc; k0 += 64) {
    __syncthreads();  // previous iteration's ds_reads done before overwrite
#pragma unroll
    for (int i = 0; i < 4; i++) {
      int c = wave * 4 + i;        // 0..15 chunk id, 1KB each
      if (c < 8) {
        int row = c * 8 + subrow;
        const char* src = (const char*)A + ((size_t)(m0 + row) * ldA + kBase + k0) * 2 +
                          (bcol ^ ((row & 7) << 4));
        gld16(src, (char*)As + c * 1024);
      } else {
        int row = (c - 8) * 8 + subrow;
        const char* src = (const char*)B + ((size_t)(n0 + row) * ldB + kBase + k0) * 2 +
                          (bcol ^ ((row & 7) << 4));
        gld16(src, (char*)Bs + (c - 8) * 1024);
      }
    }
    __syncthreads();  // compiler drains vmcnt before barrier -> LDS valid
#pragma unroll
    for (int kk = 0; kk < 2; kk++) {
      int kb = kk * 64 + l16 * 16;  // byte offset of 16B chunk within row
      half8 a[2];
#pragma unroll
      for (int m = 0; m < 2; m++) {
        int r = wr * 32 + m * 16 + l15;
        a[m] = *(half8*)((char*)As + r * 128 + (kb ^ ((r & 7) << 4)));
      }
#pragma unroll
      for (int n = 0; n < 2; n++) {
        int r = wc * 32 + n * 16 + l15;
        half8 b = *(half8*)((char*)Bs + r * 128 + (kb ^ ((r & 7) << 4)));
        acc[0][n] = __builtin_amdgcn_mfma_f32_16x16x32_f16(a[0], b, acc[0][n], 0, 0, 0);
        acc[1][n] = __builtin_amdgcn_mfma_f32_16x16x32_f16(a[1], b, acc[1][n], 0, 0, 0);
      }
    }
  }
#pragma unroll
  for (int m = 0; m < 2; m++)
#pragma unroll
    for (int n = 0; n < 2; n++)
#pragma unroll
      for (int j = 0; j < 4; j++) {
        int row = m0 + wr * 32 + m * 16 + l16 * 4 + j;
        int colI = n0 + wc * 32 + n * 16 + l15;
        if (row < M && colI < Nc) {
          size_t idx = (size_t)row * ldC + colI;
          float v = acc[m][n][j];
          if (accFlag) v += C[idx];
          if (bias) v += bias[colI];
          if (reluFlag) v = fmaxf(v, 0.f);
          C[idx] = v;
          if (dst16) dst16[(size_t)row * ld16 + colI] = f2h(v);
        }
      }
}

// ---------------- BN: pass1 partials (vectorized), reduce, apply (+fp16 out) ----------------
template <int D>
__global__ __launch_bounds__(256) void bn_part_kernel(const float* __restrict__ h,
                                                      float* __restrict__ part, int rows) {
  constexpr int TPR = D / 4;       // threads per row
  constexpr int RPI = 256 / TPR;   // rows per block-iter
  __shared__ float4 ssum[256], ssq[256];
  int tid = threadIdx.x;
  int g = tid / TPR;
  int fr = tid % TPR;
  float4 s = {0.f, 0.f, 0.f, 0.f}, q = {0.f, 0.f, 0.f, 0.f};
  for (int r = blockIdx.x * RPI + g; r < rows; r += gridDim.x * RPI) {
    float4 v = *(const float4*)(h + (size_t)r * D + fr * 4);
    s.x += v.x; s.y += v.y; s.z += v.z; s.w += v.w;
    q.x += v.x * v.x; q.y += v.y * v.y; q.z += v.z * v.z; q.w += v.w * v.w;
  }
  ssum[tid] = s; ssq[tid] = q;
  __syncthreads();
  if (g == 0) {
#pragma unroll
    for (int gg = 1; gg < RPI; gg++) {
      float4 a = ssum[gg * TPR + fr], b = ssq[gg * TPR + fr];
      s.x += a.x; s.y += a.y; s.z += a.z; s.w += a.w;
      q.x += b.x; q.y += b.y; q.z += b.z; q.w += b.w;
    }
    *(float4*)(part + (size_t)blockIdx.x * (2 * D) + fr * 4) = s;
    *(float4*)(part + (size_t)blockIdx.x * (2 * D) + D + fr * 4) = q;
  }
}

__global__ void bn_reduce_kernel(const float* __restrict__ part, float* __restrict__ acc, int D) {
  int c = blockIdx.x;   // 0..2D-1
  int tid = threadIdx.x;  // 64
  float v = 0.f;
  for (int b = tid; b < BN_B; b += 64) v += part[(size_t)b * (2 * D) + c];
#pragma unroll
  for (int off = 32; off > 0; off >>= 1) v += __shfl_down(v, off);
  if (tid == 0) {
    if (c < D) acc[c] = v;
    else acc[256 + (c - D)] = v;
  }
}

template <int D>
__global__ void bn_apply_kernel(float* __restrict__ h, const float* __restrict__ acc,
                                const float* __restrict__ gam, const float* __restrict__ bet,
                                int rows, int relu, float invRows,
                                u16* __restrict__ dst16, int ld16) {
  constexpr int F4 = D / 4;
  int i = blockIdx.x * blockDim.x + threadIdx.x;
  if (i >= rows * F4) return;
  int row = i / F4;
  int fi = (i % F4) * 4;
  float4 s4 = *(const float4*)(acc + fi);
  float4 q4 = *(const float4*)(acc + 256 + fi);
  float4 g4 = *(const float4*)(gam + fi);
  float4 b4 = *(const float4*)(bet + fi);
  float4 v = *(float4*)(h + (size_t)row * D + fi);
  float4 res;
  {
    float m = s4.x * invRows, var = q4.x * invRows - m * m;
    res.x = (v.x - m) * rsqrtf(var + EPSBN) * g4.x + b4.x;
    m = s4.y * invRows; var = q4.y * invRows - m * m;
    res.y = (v.y - m) * rsqrtf(var + EPSBN) * g4.y + b4.y;
    m = s4.z * invRows; var = q4.z * invRows - m * m;
    res.z = (v.z - m) * rsqrtf(var + EPSBN) * g4.z + b4.z;
    m = s4.w * invRows; var = q4.w * invRows - m * m;
    res.w = (v.w - m) * rsqrtf(var + EPSBN) * g4.w + b4.w;
  }
  if (relu) {
    res.x = fmaxf(res.x, 0.f); res.y = fmaxf(res.y, 0.f);
    res.z = fmaxf(res.z, 0.f); res.w = fmaxf(res.w, 0.f);
  }
  *(float4*)(h + (size_t)row * D + fi) = res;
  if (dst16) {
    ushort4 u;
    u.x = f2h(res.x); u.y = f2h(res.y); u.z = f2h(res.z); u.w = f2h(res.w);
    *(ushort4*)(dst16 + (size_t)row * ld16 + fi) = u;
  }
}

__global__ void fc3_kernel(const float* __restrict__ h, const float* __restrict__ w,
                           const float* __restrict__ b, float* __restrict__ out) {
  int node = blockIdx.x * 4 + (threadIdx.x >> 6);
  int lane = threadIdx.x & 63;
  if (node >= N_NODES) return;
  float v = h[(size_t)node * DD3 + lane] * w[lane];
#pragma unroll
  for (int off = 32; off > 0; off >>= 1) v += __shfl_down(v, off);
  if (lane == 0) out[node] = v + b[0];
}

// ---------------- host ----------------
extern "C" void kernel_launch(void* const* d_in, const int* in_sizes, int n_in,
                              void* d_out, int out_size, void* d_ws, size_t ws_size,
                              hipStream_t stream) {
  const float* x = (const float*)d_in[0];
  const void* ei = d_in[1];
  const float* conv1_w = (const float*)d_in[2];
  const float* convs_w = (const float*)d_in[3];
  const float* convs_b = (const float*)d_in[4];
  const float* bn1_g = (const float*)d_in[5];
  const float* bn1_b = (const float*)d_in[6];
  const float* fc1_w = (const float*)d_in[7];
  const float* fc1_b = (const float*)d_in[8];
  const float* bn2_g = (const float*)d_in[9];
  const float* bn2_b = (const float*)d_in[10];
  const float* fc2_w = (const float*)d_in[11];
  const float* fc2_b = (const float*)d_in[12];
  const float* bn3_g = (const float*)d_in[13];
  const float* bn3_b = (const float*)d_in[14];
  const float* fc3_w = (const float*)d_in[15];
  const float* fc3_b = (const float*)d_in[16];
  float* out = (float*)d_out;

  char* ws = (char*)d_ws;
  size_t off = 0;
  auto alloc = [&](size_t bytes) -> void* {
    off = (off + 255) & ~(size_t)255;
    void* p = ws + off;
    off += bytes;
    return p;
  };
  u16* Tcat = (u16*)alloc((size_t)(N_NODES + 64) * 10 * DD1 * 2);  // 10 fp16 slots, ~103 MB
  float* bufA = (float*)alloc((size_t)N_NODES * DD1 * 4);
  float* bufB = (float*)alloc((size_t)N_NODES * DD1 * 4);
  float* f1buf = (float*)alloc((size_t)N_NODES * DD2 * 4);
  float* f2buf = (float*)alloc((size_t)N_NODES * DD3 * 4);
  u16* h16 = (u16*)alloc((size_t)(N_NODES + 64) * DD1 * 2);       // fc1 input fp16
  u16* h16b = (u16*)alloc((size_t)(N_NODES + 64) * DD2 * 2);      // fc2 input fp16
  u16* Wt = (u16*)alloc((size_t)(1280 * 256 + 3 * 2560 * 256) * 2);
  u16* Wtf1 = (u16*)alloc((size_t)DD2 * DD1 * 2);                 // [128][256]
  u16* Wtf2 = (u16*)alloc((size_t)128 * DD2 * 2);                 // [64 valid +pad][128]
  float* bnpart = (float*)alloc((size_t)BN_B * 2 * DD1 * 4);
  int* ideg = (int*)alloc(N_NODES * 4);
  int* idegP = (int*)alloc(N_NODES * 4);
  int* rowptr = (int*)alloc((N_NODES + 1) * 4);
  int* cnt = (int*)alloc(N_NODES * 4);
  int* col = (int*)alloc(E_PAD * 4);
  float* wcsr = (float*)alloc(E_PAD * 4);
  float* dinv = (float*)alloc(N_NODES * 4);
  float* bnacc = (float*)alloc(512 * 4);
  int* flag = (int*)alloc(4);
  if (off > ws_size) return;

  // ---- one-time weight transpose to fp16 ----
  wt_kernel<<<dim3(1280 / 32, 8), 256, 0, stream>>>(conv1_w, Wt, 1280, 256);
  for (int l = 0; l < 3; l++)
    wt_kernel<<<dim3(2560 / 32, 8), 256, 0, stream>>>(convs_w + (size_t)l * 655360,
                                                      Wt + 327680 + (size_t)l * 655360, 2560, 256);
  wt_kernel<<<dim3(256 / 32, 128 / 32), 256, 0, stream>>>(fc1_w, Wtf1, 256, 128);
  wt_kernel<<<dim3(128 / 32, 64 / 32), 256, 0, stream>>>(fc2_w, Wtf2, 128, 64);

  // ---- graph structures (padded CSR) ----
  hipMemsetAsync(ideg, 0, N_NODES * 4, stream);
  hipMemsetAsync(cnt, 0, N_NODES * 4, stream);
  detect_idx_kernel<<<1, 64, 0, stream>>>(ei, flag);
  deg_kernel<<<(N_EDGES + 255) / 256, 256, 0, stream>>>(ei, flag, ideg);
  dinv_kernel<<<(N_NODES + 255) / 256, 256, 0, stream>>>(ideg, dinv, idegP);
  scan_kernel<<<1, 1024, 0, stream>>>(idegP, rowptr);
  fill_csr_kernel<<<(N_EDGES + 255) / 256, 256, 0, stream>>>(ei, flag, dinv, rowptr, cnt, col, wcsr);
  pad_csr_kernel<<<(N_NODES + 255) / 256, 256, 0, stream>>>(ideg, rowptr, col, wcsr);

  auto lhat = [&](int F, float scale, int inS, int tx0S, int outS) {
    if (F == 128) {
      // SLICES=2, NPG=5000, 32 nodes/block -> 157 blocks/role
      if (tx0S < 0)
        lhat8_kernel<128, false><<<8 * 157, 256, 0, stream>>>(Tcat, rowptr, col, wcsr, scale,
                                                              inS * 128, 0, outS * 128);
      else
        lhat8_kernel<128, true><<<8 * 157, 256, 0, stream>>>(Tcat, rowptr, col, wcsr, scale,
                                                             inS * 128, tx0S * 128, outS * 128);
    } else {
      // SLICES=4, NPG=10000, 32 nodes/block -> 313 blocks/role
      if (tx0S < 0)
        lhat8_kernel<256, false><<<8 * 313, 256, 0, stream>>>(Tcat, rowptr, col, wcsr, scale,
                                                              inS * 256, 0, outS * 256);
      else
        lhat8_kernel<256, true><<<8 * 313, 256, 0, stream>>>(Tcat, rowptr, col, wcsr, scale,
                                                             inS * 256, tx0S * 256, outS * 256);
    }
  };
  // generalized f16 MFMA gemm launch (XCD-chunked 1-D grid)
  auto mgemm = [&](const u16* A, int ldA, const u16* B, int ldB, int kBase, int Kc,
                   float* C, int ldC, int Nc, const float* bias, int accFlag, int relu,
                   u16* dst16, int ld16) {
    int NX = (N_NODES + 63) / 64;        // 313
    int NXP = (NX + 7) & ~7;             // 320
    int NY = (Nc + 63) / 64;
    gemm_cat_kernel<<<dim3(NXP * NY), 256, 0, stream>>>(A, ldA, B, ldB, kBase, Kc, C, ldC, Nc,
                                                        bias, N_NODES, NX, NY, accFlag, relu,
                                                        dst16, ld16);
  };
  // per layer: T0..T9 in slots 0..9, then ONE full-K GEMM
  auto cheb = [&](int F, const u16* WtL, const float* bias, float* hout, int relu,
                  u16* dst16, int ld16) {
    lhat(F, 1.f, 0, -1, 1);                                          // T1
    for (int k = 2; k < K_CHEB; k++) lhat(F, 2.f, k - 1, k - 2, k);  // T2..T9
    mgemm(Tcat, 10 * F, WtL, 10 * F, 0, 10 * F, hout, 256, 256, bias, 0, relu, dst16, ld16);
  };
  auto bn = [&](float* h, int D, const float* g, const float* b, int relu, u16* dst16, int ld16) {
    if (D == 256) {
      bn_part_kernel<256><<<BN_B, 256, 0, stream>>>(h, bnpart, N_NODES);
      bn_reduce_kernel<<<2 * 256, 64, 0, stream>>>(bnpart, bnacc, 256);
      bn_apply_kernel<256><<<(N_NODES * 64 + 255) / 256, 256, 0, stream>>>(
          h, bnacc, g, b, N_NODES, relu, 1.f / N_NODES, dst16, ld16);
    } else if (D == 128) {
      bn_part_kernel<128><<<BN_B, 256, 0, stream>>>(h, bnpart, N_NODES);
      bn_reduce_kernel<<<2 * 128, 64, 0, stream>>>(bnpart, bnacc, 128);
      bn_apply_kernel<128><<<(N_NODES * 32 + 255) / 256, 256, 0, stream>>>(
          h, bnacc, g, b, N_NODES, relu, 1.f / N_NODES, dst16, ld16);
    } else {
      bn_part_kernel<64><<<BN_B, 256, 0, stream>>>(h, bnpart, N_NODES);
      bn_reduce_kernel<<<2 * 64, 64, 0, stream>>>(bnpart, bnacc, 64);
      bn_apply_kernel<64><<<(N_NODES * 16 + 255) / 256, 256, 0, stream>>>(
          h, bnacc, g, b, N_NODES, relu, 1.f / N_NODES, dst16, ld16);
    }
  };

  // ---- conv1: T0 = x (fp16 convert), cheb(128->256)+relu; epilogue writes T0 slot direct ----
  convert_cat_kernel<128><<<1250, 256, 0, stream>>>(x, Tcat);
  cheb(FDIM_IN, Wt, nullptr, bufA, 1, Tcat, 10 * DD1);

  // ---- conv2: cheb(256->256)+bias+relu -> bufB, bn1 (writes slot0 for conv3) ----
  cheb(DD1, Wt + 327680, convs_b, bufB, 1, nullptr, 0);
  bn(bufB, DD1, bn1_g, bn1_b, 0, Tcat, 10 * DD1);

  // ---- conv3 ----
  cheb(DD1, Wt + 327680 + 655360, convs_b + DD1, bufA, 1, nullptr, 0);
  bn(bufA, DD1, bn1_g, bn1_b, 0, Tcat, 10 * DD1);

  // ---- conv4 (bn writes h16 for fc1) ----
  cheb(DD1, Wt + 327680 + 2 * 655360, convs_b + 2 * DD1, bufB, 1, nullptr, 0);
  bn(bufB, DD1, bn1_g, bn1_b, 0, h16, DD1);

  // ---- fc1 (256->128) + bias, bn2+relu (writes h16b for fc2) ----
  mgemm(h16, DD1, Wtf1, DD1, 0, DD1, f1buf, DD2, DD2, fc1_b, 0, 0, nullptr, 0);
  bn(f1buf, DD2, bn2_g, bn2_b, 1, h16b, DD2);

  // ---- fc2 (128->64) + bias, bn3 ----
  mgemm(h16b, DD2, Wtf2, DD2, 0, DD2, f2buf, DD3, DD3, fc2_b, 0, 0, nullptr, 0);
  bn(f2buf, DD3, bn3_g, bn3_b, 0, nullptr, 0);

  // ---- fc3 (64->1) ----
  fc3_kernel<<<(N_NODES + 3) / 4, 256, 0, stream>>>(f2buf, fc3_w, fc3_b, out);
}

// Round 19
// 901.347 us; speedup vs baseline: 1.0429x; 1.0429x over previous
//
#include <hip/hip_runtime.h>
#include <hip/hip_bf16.h>
#include <stdint.h>

// ChebNet: fp16 Chebyshev T-storage, 10-slot flat concat buffer, single full-K
// f16 MFMA GEMM per conv layer, two-pass BN, fp16 MFMA head.
// R19: packed CSR retry (col|fp16w in one u32) on the KNOWN-GOOD R18 base.
// R16/R17 forensics: dbuf GEMM (abandoned) caused the 0.29 failures; fp16
// weight marginal was only +0.005. Single-variable test vs R18.

#define N_NODES 20000
#define N_EDGES 320000
#define FDIM_IN 128
#define DD1 256
#define DD2 128
#define DD3 64
#define K_CHEB 10
#define EPSBN 1e-5f
#define BN_B 512  // partial blocks for BN pass1
#define E_PAD (N_EDGES + 8 * N_NODES)  // padded-CSR capacity

typedef unsigned short u16;
typedef unsigned int u32;
typedef _Float16 half8 __attribute__((ext_vector_type(8)));
typedef __attribute__((ext_vector_type(4))) float floatx4;

__device__ __forceinline__ u16 f2h(float v) {
  _Float16 h = (_Float16)v;
  return *reinterpret_cast<u16*>(&h);
}

__device__ __forceinline__ float h2f(u16 b) {
  _Float16 h = *reinterpret_cast<_Float16*>(&b);
  return (float)h;
}

__device__ __forceinline__ void gld16(const void* g, void* l) {
  __builtin_amdgcn_global_load_lds((const __attribute__((address_space(1))) u32*)g,
                                   (__attribute__((address_space(3))) u32*)l, 16, 0, 0);
}

// ---------------- graph setup ----------------
__global__ void detect_idx_kernel(const void* ei, int* flag) {
  int t = threadIdx.x;
  const int* p = (const int*)ei;
  int v = p[2 * t + 1];
  unsigned long long b = __ballot(v == 0);
  if (t == 0) *flag = (b == ~0ULL) ? 1 : 0;
}

__device__ __forceinline__ int load_edge(const void* ei, int mode64, long long pos) {
  return mode64 ? (int)((const long long*)ei)[pos] : ((const int*)ei)[pos];
}

__global__ void deg_kernel(const void* ei, const int* __restrict__ flag, int* __restrict__ ideg) {
  int e = blockIdx.x * blockDim.x + threadIdx.x;
  if (e < N_EDGES) {
    int d = load_edge(ei, *flag, (long long)N_EDGES + e);
    atomicAdd(&ideg[d], 1);
  }
}

// dinv from REAL degree; idegP = degree padded up to multiple of 8
__global__ void dinv_kernel(const int* __restrict__ ideg, float* __restrict__ dinv,
                            int* __restrict__ idegP) {
  int n = blockIdx.x * blockDim.x + threadIdx.x;
  if (n < N_NODES) {
    int d = ideg[n];
    dinv[n] = d > 0 ? rsqrtf((float)d) : 0.f;
    idegP[n] = (d + 7) & ~7;
  }
}

__global__ __launch_bounds__(1024) void scan_kernel(const int* __restrict__ ideg, int* __restrict__ rowptr) {
  __shared__ int part[1024];
  int tid = threadIdx.x;
  const int CH = (N_NODES + 1023) / 1024;
  int base = tid * CH;
  int s = 0;
  for (int i = 0; i < CH; i++) { int idx = base + i; if (idx < N_NODES) s += ideg[idx]; }
  part[tid] = s;
  __syncthreads();
  for (int off = 1; off < 1024; off <<= 1) {
    int v = (tid >= off) ? part[tid - off] : 0;
    __syncthreads();
    part[tid] += v;
    __syncthreads();
  }
  int run = (tid == 0) ? 0 : part[tid - 1];
  for (int i = 0; i < CH; i++) { int idx = base + i; if (idx < N_NODES) { rowptr[idx] = run; run += ideg[idx]; } }
  if (tid == 1023) rowptr[N_NODES] = run;
}

// packed CSR entry: low16 = col (N<2^15), high16 = fp16 weight
__global__ void fill_csr_kernel(const void* ei, const int* __restrict__ flag,
                                const float* __restrict__ dinv, const int* __restrict__ rowptr,
                                int* __restrict__ cnt, u32* __restrict__ pcw) {
  int e = blockIdx.x * blockDim.x + threadIdx.x;
  if (e < N_EDGES) {
    int m = *flag;
    int s = load_edge(ei, m, e);
    int d = load_edge(ei, m, (long long)N_EDGES + e);
    int pos = rowptr[d] + atomicAdd(&cnt[d], 1);
    float w = -dinv[s] * dinv[d];
    pcw[pos] = (u32)s | ((u32)f2h(w) << 16);
  }
}

// fill pad slots [beg+deg .. beg+degP) with col=self, w=+0.0h (exact no-op adds)
__global__ void pad_csr_kernel(const int* __restrict__ ideg, const int* __restrict__ rowptr,
                               u32* __restrict__ pcw) {
  int n = blockIdx.x * blockDim.x + threadIdx.x;
  if (n < N_NODES) {
    int d = ideg[n];
    int beg = rowptr[n], end = rowptr[n + 1];
    for (int e = beg + d; e < end; e++) pcw[e] = (u32)n;
  }
}

// ---------------- weight transpose-convert: W[KF][Nd] fp32 -> Wt[Nd][KF] fp16 ----------------
__global__ __launch_bounds__(256) void wt_kernel(const float* __restrict__ W, u16* __restrict__ Wt,
                                                 int KF, int Nd) {
  __shared__ float sm[32][36];
  int kf0 = blockIdx.x * 32, n0 = blockIdx.y * 32;
  int r = threadIdx.x >> 3, c4 = (threadIdx.x & 7) * 4;
  float4 v = *(const float4*)(W + (size_t)(kf0 + r) * Nd + n0 + c4);
  sm[r][c4 + 0] = v.x; sm[r][c4 + 1] = v.y; sm[r][c4 + 2] = v.z; sm[r][c4 + 3] = v.w;
  __syncthreads();
  int on = threadIdx.x >> 3, okf4 = (threadIdx.x & 7) * 4;
  ushort4 u;
  u.x = f2h(sm[okf4 + 0][on]);
  u.y = f2h(sm[okf4 + 1][on]);
  u.z = f2h(sm[okf4 + 2][on]);
  u.w = f2h(sm[okf4 + 3][on]);
  *(ushort4*)(Wt + (size_t)(n0 + on) * KF + kf0 + okf4) = u;
}

// ---------------- convert h fp32 -> fp16 into cat slot 0 (T0); row stride 10F ----------------
template <int F>
__global__ void convert_cat_kernel(const float* __restrict__ in, u16* __restrict__ cat) {
  constexpr int F8 = F / 8;
  int i = blockIdx.x * blockDim.x + threadIdx.x;  // over N*F8
  int n = i / F8, f8 = i % F8;
  const float4* p = (const float4*)(in + (size_t)n * F + f8 * 8);
  float4 a = p[0], b = p[1];
  half8 o;
  o[0] = (_Float16)a.x; o[1] = (_Float16)a.y; o[2] = (_Float16)a.z; o[3] = (_Float16)a.w;
  o[4] = (_Float16)b.x; o[5] = (_Float16)b.y; o[6] = (_Float16)b.z; o[7] = (_Float16)b.w;
  *(half8*)(cat + (size_t)n * (10 * F) + f8 * 8) = o;
}

// ---------------- L_hat, XCD-sliced, padded+packed CSR, software-pipelined ----------------
// slot_out = scale * gather(slot_in) - slot_tx0. blockIdx%8 -> XCD role
// (feature-slice q x node group grp); slice data L2-resident.
template <int F, bool HAS_TX0>
__global__ void lhat9_kernel(u16* __restrict__ cat,
                             const int* __restrict__ rowptr, const u32* __restrict__ pcw,
                             float scale, int inOff, int tx0Off, int outOff) {
  constexpr int R = 10 * F;                  // cat row stride (halves)
  constexpr int SLICES = F / 64;             // 4 (F=256) or 2 (F=128)
  constexpr int NPG = N_NODES * SLICES / 8;  // 10000 (F=256) / 5000 (F=128)
  int xcd = blockIdx.x & 7;
  int lb = blockIdx.x >> 3;
  int q = xcd % SLICES;
  int grp = xcd / SLICES;
  int node0 = grp * NPG;
  int node = node0 + lb * 32 + (threadIdx.x >> 3);
  if (node >= node0 + NPG || node >= N_NODES) return;
  int ln8 = q * 64 + (threadIdx.x & 7) * 8;  // element offset within a slot
  int beg = rowptr[node], end = rowptr[node + 1];  // multiple of 8 (>=8)
  float acc[8] = {0.f, 0.f, 0.f, 0.f, 0.f, 0.f, 0.f, 0.f};

  // prologue: load batch 0
  u32 pk[8];
  half8 v[8];
#pragma unroll
  for (int j = 0; j < 8; j++) {
    pk[j] = pcw[beg + j];
    v[j] = *(const half8*)(cat + (size_t)(pk[j] & 0xFFFFu) * R + inOff + ln8);
  }
  for (int e = beg + 8; e < end; e += 8) {
    u32 pk2[8];
    half8 v2[8];
#pragma unroll
    for (int j = 0; j < 8; j++) {
      pk2[j] = pcw[e + j];
      v2[j] = *(const half8*)(cat + (size_t)(pk2[j] & 0xFFFFu) * R + inOff + ln8);
    }
#pragma unroll
    for (int j = 0; j < 8; j++) {
      float wv = h2f((u16)(pk[j] >> 16));
#pragma unroll
      for (int i = 0; i < 8; i++) acc[i] += wv * (float)v[j][i];
    }
#pragma unroll
    for (int j = 0; j < 8; j++) { pk[j] = pk2[j]; v[j] = v2[j]; }
  }
#pragma unroll
  for (int j = 0; j < 8; j++) {
    float wv = h2f((u16)(pk[j] >> 16));
#pragma unroll
    for (int i = 0; i < 8; i++) acc[i] += wv * (float)v[j][i];
  }

  float r[8];
#pragma unroll
  for (int i = 0; i < 8; i++) r[i] = scale * acc[i];
  if (HAS_TX0) {
    half8 t = *(const half8*)(cat + (size_t)node * R + tx0Off + ln8);
#pragma unroll
    for (int i = 0; i < 8; i++) r[i] -= (float)t[i];
  }
  half8 o;
#pragma unroll
  for (int i = 0; i < 8; i++) o[i] = (_Float16)r[i];
  *(half8*)(cat + (size_t)node * R + outOff + ln8) = o;
}

// ---------------- f16 MFMA GEMM: C[M][ldC] = A[M][ldA]f16(Kc cols) @ B[Nc][ldB]^T ----------------
// Tile 64(M) x 64(N) x 64(K); 4 waves (2x2), each 32x32. 1-D grid with
// XCD-chunked swizzle. Single-buffered staging (known-good): stage -> barrier
// -> compute. Optional fp16 epilogue copy.
__global__ __launch_bounds__(256) void gemm_cat_kernel(
    const u16* __restrict__ A, int ldA, const u16* __restrict__ B, int ldB, int kBase,
    int Kc, float* __restrict__ C, int ldC, int Nc, const float* __restrict__ bias, int M,
    int NX, int NY, int accFlag, int reluFlag, u16* __restrict__ dst16, int ld16) {
  __shared__ __align__(16) u16 As[64 * 64];    // 8 KB
  __shared__ __align__(16) u16 Bs[64 * 64];    // 8 KB
  int pid = blockIdx.x;
  int g8 = 8 * NY;
  int a8 = pid / g8, rem = pid % g8;
  int by = rem >> 3;
  int bx = a8 * 8 + (rem & 7);
  if (bx >= NX) return;
  int tid = threadIdx.x;
  int lane = tid & 63, wave = tid >> 6;
  int wr = wave >> 1, wc = wave & 1;
  int l15 = lane & 15, l16 = lane >> 4;
  int m0 = bx * 64, n0 = by * 64;
  floatx4 acc[2][2];
#pragma unroll
  for (int m = 0; m < 2; m++)
#pragma unroll
    for (int n = 0; n < 2; n++) acc[m][n] = (floatx4){0.f, 0.f, 0.f, 0.f};

  int subrow = lane >> 3;          // 0..7
  int bcol = (lane & 7) * 16;      // byte col within 128B row

  for (int k0 = 0; k0 < Kc; k0 += 64) {
    __syncthreads();  // previous iteration's ds_reads done before overwrite
#pragma unroll
    for (int i = 0; i < 4; i++) {
      int c = wave * 4 + i;        // 0..15 chunk id, 1KB each
      if (c < 8) {
        int row = c * 8 + subrow;
        const char* src = (const char*)A + ((size_t)(m0 + row) * ldA + kBase + k0) * 2 +
                          (bcol ^ ((row & 7) << 4));
        gld16(src, (char*)As + c * 1024);
      } else {
        int row = (c - 8) * 8 + subrow;
        const char* src = (const char*)B + ((size_t)(n0 + row) * ldB + kBase + k0) * 2 +
                          (bcol ^ ((row & 7) << 4));
        gld16(src, (char*)Bs + (c - 8) * 1024);
      }
    }
    __syncthreads();  // compiler drains vmcnt before barrier -> LDS valid
#pragma unroll
    for (int kk = 0; kk < 2; kk++) {
      int kb = kk * 64 + l16 * 16;  // byte offset of 16B chunk within row
      half8 a[2];
#pragma unroll
      for (int m = 0; m < 2; m++) {
        int r = wr * 32 + m * 16 + l15;
        a[m] = *(half8*)((char*)As + r * 128 + (kb ^ ((r & 7) << 4)));
      }
#pragma unroll
      for (int n = 0; n < 2; n++) {
        int r = wc * 32 + n * 16 + l15;
        half8 b = *(half8*)((char*)Bs + r * 128 + (kb ^ ((r & 7) << 4)));
        acc[0][n] = __builtin_amdgcn_mfma_f32_16x16x32_f16(a[0], b, acc[0][n], 0, 0, 0);
        acc[1][n] = __builtin_amdgcn_mfma_f32_16x16x32_f16(a[1], b, acc[1][n], 0, 0, 0);
      }
    }
  }
#pragma unroll
  for (int m = 0; m < 2; m++)
#pragma unroll
    for (int n = 0; n < 2; n++)
#pragma unroll
      for (int j = 0; j < 4; j++) {
        int row = m0 + wr * 32 + m * 16 + l16 * 4 + j;
        int colI = n0 + wc * 32 + n * 16 + l15;
        if (row < M && colI < Nc) {
          size_t idx = (size_t)row * ldC + colI;
          float v = acc[m][n][j];
          if (accFlag) v += C[idx];
          if (bias) v += bias[colI];
          if (reluFlag) v = fmaxf(v, 0.f);
          C[idx] = v;
          if (dst16) dst16[(size_t)row * ld16 + colI] = f2h(v);
        }
      }
}

// ---------------- BN: pass1 partials (vectorized), reduce, apply (+fp16 out) ----------------
template <int D>
__global__ __launch_bounds__(256) void bn_part_kernel(const float* __restrict__ h,
                                                      float* __restrict__ part, int rows) {
  constexpr int TPR = D / 4;       // threads per row
  constexpr int RPI = 256 / TPR;   // rows per block-iter
  __shared__ float4 ssum[256], ssq[256];
  int tid = threadIdx.x;
  int g = tid / TPR;
  int fr = tid % TPR;
  float4 s = {0.f, 0.f, 0.f, 0.f}, q = {0.f, 0.f, 0.f, 0.f};
  for (int r = blockIdx.x * RPI + g; r < rows; r += gridDim.x * RPI) {
    float4 v = *(const float4*)(h + (size_t)r * D + fr * 4);
    s.x += v.x; s.y += v.y; s.z += v.z; s.w += v.w;
    q.x += v.x * v.x; q.y += v.y * v.y; q.z += v.z * v.z; q.w += v.w * v.w;
  }
  ssum[tid] = s; ssq[tid] = q;
  __syncthreads();
  if (g == 0) {
#pragma unroll
    for (int gg = 1; gg < RPI; gg++) {
      float4 a = ssum[gg * TPR + fr], b = ssq[gg * TPR + fr];
      s.x += a.x; s.y += a.y; s.z += a.z; s.w += a.w;
      q.x += b.x; q.y += b.y; q.z += b.z; q.w += b.w;
    }
    *(float4*)(part + (size_t)blockIdx.x * (2 * D) + fr * 4) = s;
    *(float4*)(part + (size_t)blockIdx.x * (2 * D) + D + fr * 4) = q;
  }
}

__global__ void bn_reduce_kernel(const float* __restrict__ part, float* __restrict__ acc, int D) {
  int c = blockIdx.x;   // 0..2D-1
  int tid = threadIdx.x;  // 64
  float v = 0.f;
  for (int b = tid; b < BN_B; b += 64) v += part[(size_t)b * (2 * D) + c];
#pragma unroll
  for (int off = 32; off > 0; off >>= 1) v += __shfl_down(v, off);
  if (tid == 0) {
    if (c < D) acc[c] = v;
    else acc[256 + (c - D)] = v;
  }
}

template <int D>
__global__ void bn_apply_kernel(float* __restrict__ h, const float* __restrict__ acc,
                                const float* __restrict__ gam, const float* __restrict__ bet,
                                int rows, int relu, float invRows,
                                u16* __restrict__ dst16, int ld16) {
  constexpr int F4 = D / 4;
  int i = blockIdx.x * blockDim.x + threadIdx.x;
  if (i >= rows * F4) return;
  int row = i / F4;
  int fi = (i % F4) * 4;
  float4 s4 = *(const float4*)(acc + fi);
  float4 q4 = *(const float4*)(acc + 256 + fi);
  float4 g4 = *(const float4*)(gam + fi);
  float4 b4 = *(const float4*)(bet + fi);
  float4 v = *(float4*)(h + (size_t)row * D + fi);
  float4 res;
  {
    float m = s4.x * invRows, var = q4.x * invRows - m * m;
    res.x = (v.x - m) * rsqrtf(var + EPSBN) * g4.x + b4.x;
    m = s4.y * invRows; var = q4.y * invRows - m * m;
    res.y = (v.y - m) * rsqrtf(var + EPSBN) * g4.y + b4.y;
    m = s4.z * invRows; var = q4.z * invRows - m * m;
    res.z = (v.z - m) * rsqrtf(var + EPSBN) * g4.z + b4.z;
    m = s4.w * invRows; var = q4.w * invRows - m * m;
    res.w = (v.w - m) * rsqrtf(var + EPSBN) * g4.w + b4.w;
  }
  if (relu) {
    res.x = fmaxf(res.x, 0.f); res.y = fmaxf(res.y, 0.f);
    res.z = fmaxf(res.z, 0.f); res.w = fmaxf(res.w, 0.f);
  }
  *(float4*)(h + (size_t)row * D + fi) = res;
  if (dst16) {
    ushort4 u;
    u.x = f2h(res.x); u.y = f2h(res.y); u.z = f2h(res.z); u.w = f2h(res.w);
    *(ushort4*)(dst16 + (size_t)row * ld16 + fi) = u;
  }
}

__global__ void fc3_kernel(const float* __restrict__ h, const float* __restrict__ w,
                           const float* __restrict__ b, float* __restrict__ out) {
  int node = blockIdx.x * 4 + (threadIdx.x >> 6);
  int lane = threadIdx.x & 63;
  if (node >= N_NODES) return;
  float v = h[(size_t)node * DD3 + lane] * w[lane];
#pragma unroll
  for (int off = 32; off > 0; off >>= 1) v += __shfl_down(v, off);
  if (lane == 0) out[node] = v + b[0];
}

// ---------------- host ----------------
extern "C" void kernel_launch(void* const* d_in, const int* in_sizes, int n_in,
                              void* d_out, int out_size, void* d_ws, size_t ws_size,
                              hipStream_t stream) {
  const float* x = (const float*)d_in[0];
  const void* ei = d_in[1];
  const float* conv1_w = (const float*)d_in[2];
  const float* convs_w = (const float*)d_in[3];
  const float* convs_b = (const float*)d_in[4];
  const float* bn1_g = (const float*)d_in[5];
  const float* bn1_b = (const float*)d_in[6];
  const float* fc1_w = (const float*)d_in[7];
  const float* fc1_b = (const float*)d_in[8];
  const float* bn2_g = (const float*)d_in[9];
  const float* bn2_b = (const float*)d_in[10];
  const float* fc2_w = (const float*)d_in[11];
  const float* fc2_b = (const float*)d_in[12];
  const float* bn3_g = (const float*)d_in[13];
  const float* bn3_b = (const float*)d_in[14];
  const float* fc3_w = (const float*)d_in[15];
  const float* fc3_b = (const float*)d_in[16];
  float* out = (float*)d_out;

  char* ws = (char*)d_ws;
  size_t off = 0;
  auto alloc = [&](size_t bytes) -> void* {
    off = (off + 255) & ~(size_t)255;
    void* p = ws + off;
    off += bytes;
    return p;
  };
  u16* Tcat = (u16*)alloc((size_t)(N_NODES + 64) * 10 * DD1 * 2);  // 10 fp16 slots, ~103 MB
  float* bufA = (float*)alloc((size_t)N_NODES * DD1 * 4);
  float* bufB = (float*)alloc((size_t)N_NODES * DD1 * 4);
  float* f1buf = (float*)alloc((size_t)N_NODES * DD2 * 4);
  float* f2buf = (float*)alloc((size_t)N_NODES * DD3 * 4);
  u16* h16 = (u16*)alloc((size_t)(N_NODES + 64) * DD1 * 2);       // fc1 input fp16
  u16* h16b = (u16*)alloc((size_t)(N_NODES + 64) * DD2 * 2);      // fc2 input fp16
  u16* Wt = (u16*)alloc((size_t)(1280 * 256 + 3 * 2560 * 256) * 2);
  u16* Wtf1 = (u16*)alloc((size_t)DD2 * DD1 * 2);                 // [128][256]
  u16* Wtf2 = (u16*)alloc((size_t)128 * DD2 * 2);                 // [64 valid +pad][128]
  float* bnpart = (float*)alloc((size_t)BN_B * 2 * DD1 * 4);
  int* ideg = (int*)alloc(N_NODES * 4);
  int* idegP = (int*)alloc(N_NODES * 4);
  int* rowptr = (int*)alloc((N_NODES + 1) * 4);
  int* cnt = (int*)alloc(N_NODES * 4);
  u32* pcw = (u32*)alloc(E_PAD * 4);
  float* dinv = (float*)alloc(N_NODES * 4);
  float* bnacc = (float*)alloc(512 * 4);
  int* flag = (int*)alloc(4);
  if (off > ws_size) return;

  // ---- one-time weight transpose to fp16 ----
  wt_kernel<<<dim3(1280 / 32, 8), 256, 0, stream>>>(conv1_w, Wt, 1280, 256);
  for (int l = 0; l < 3; l++)
    wt_kernel<<<dim3(2560 / 32, 8), 256, 0, stream>>>(convs_w + (size_t)l * 655360,
                                                      Wt + 327680 + (size_t)l * 655360, 2560, 256);
  wt_kernel<<<dim3(256 / 32, 128 / 32), 256, 0, stream>>>(fc1_w, Wtf1, 256, 128);
  wt_kernel<<<dim3(128 / 32, 64 / 32), 256, 0, stream>>>(fc2_w, Wtf2, 128, 64);

  // ---- graph structures (padded+packed CSR) ----
  hipMemsetAsync(ideg, 0, N_NODES * 4, stream);
  hipMemsetAsync(cnt, 0, N_NODES * 4, stream);
  detect_idx_kernel<<<1, 64, 0, stream>>>(ei, flag);
  deg_kernel<<<(N_EDGES + 255) / 256, 256, 0, stream>>>(ei, flag, ideg);
  dinv_kernel<<<(N_NODES + 255) / 256, 256, 0, stream>>>(ideg, dinv, idegP);
  scan_kernel<<<1, 1024, 0, stream>>>(idegP, rowptr);
  fill_csr_kernel<<<(N_EDGES + 255) / 256, 256, 0, stream>>>(ei, flag, dinv, rowptr, cnt, pcw);
  pad_csr_kernel<<<(N_NODES + 255) / 256, 256, 0, stream>>>(ideg, rowptr, pcw);

  auto lhat = [&](int F, float scale, int inS, int tx0S, int outS) {
    if (F == 128) {
      // SLICES=2, NPG=5000, 32 nodes/block -> 157 blocks/role
      if (tx0S < 0)
        lhat9_kernel<128, false><<<8 * 157, 256, 0, stream>>>(Tcat, rowptr, pcw, scale,
                                                              inS * 128, 0, outS * 128);
      else
        lhat9_kernel<128, true><<<8 * 157, 256, 0, stream>>>(Tcat, rowptr, pcw, scale,
                                                             inS * 128, tx0S * 128, outS * 128);
    } else {
      // SLICES=4, NPG=10000, 32 nodes/block -> 313 blocks/role
      if (tx0S < 0)
        lhat9_kernel<256, false><<<8 * 313, 256, 0, stream>>>(Tcat, rowptr, pcw, scale,
                                                              inS * 256, 0, outS * 256);
      else
        lhat9_kernel<256, true><<<8 * 313, 256, 0, stream>>>(Tcat, rowptr, pcw, scale,
                                                             inS * 256, tx0S * 256, outS * 256);
    }
  };
  // generalized f16 MFMA gemm launch (XCD-chunked 1-D grid)
  auto mgemm = [&](const u16* A, int ldA, const u16* B, int ldB, int kBase, int Kc,
                   float* C, int ldC, int Nc, const float* bias, int accFlag, int relu,
                   u16* dst16, int ld16) {
    int NX = (N_NODES + 63) / 64;        // 313
    int NXP = (NX + 7) & ~7;             // 320
    int NY = (Nc + 63) / 64;
    gemm_cat_kernel<<<dim3(NXP * NY), 256, 0, stream>>>(A, ldA, B, ldB, kBase, Kc, C, ldC, Nc,
                                                        bias, N_NODES, NX, NY, accFlag, relu,
                                                        dst16, ld16);
  };
  // per layer: T0..T9 in slots 0..9, then ONE full-K GEMM
  auto cheb = [&](int F, const u16* WtL, const float* bias, float* hout, int relu,
                  u16* dst16, int ld16) {
    lhat(F, 1.f, 0, -1, 1);                                          // T1
    for (int k = 2; k < K_CHEB; k++) lhat(F, 2.f, k - 1, k - 2, k);  // T2..T9
    mgemm(Tcat, 10 * F, WtL, 10 * F, 0, 10 * F, hout, 256, 256, bias, 0, relu, dst16, ld16);
  };
  auto bn = [&](float* h, int D, const float* g, const float* b, int relu, u16* dst16, int ld16) {
    if (D == 256) {
      bn_part_kernel<256><<<BN_B, 256, 0, stream>>>(h, bnpart, N_NODES);
      bn_reduce_kernel<<<2 * 256, 64, 0, stream>>>(bnpart, bnacc, 256);
      bn_apply_kernel<256><<<(N_NODES * 64 + 255) / 256, 256, 0, stream>>>(
          h, bnacc, g, b, N_NODES, relu, 1.f / N_NODES, dst16, ld16);
    } else if (D == 128) {
      bn_part_kernel<128><<<BN_B, 256, 0, stream>>>(h, bnpart, N_NODES);
      bn_reduce_kernel<<<2 * 128, 64, 0, stream>>>(bnpart, bnacc, 128);
      bn_apply_kernel<128><<<(N_NODES * 32 + 255) / 256, 256, 0, stream>>>(
          h, bnacc, g, b, N_NODES, relu, 1.f / N_NODES, dst16, ld16);
    } else {
      bn_part_kernel<64><<<BN_B, 256, 0, stream>>>(h, bnpart, N_NODES);
      bn_reduce_kernel<<<2 * 64, 64, 0, stream>>>(bnpart, bnacc, 64);
      bn_apply_kernel<64><<<(N_NODES * 16 + 255) / 256, 256, 0, stream>>>(
          h, bnacc, g, b, N_NODES, relu, 1.f / N_NODES, dst16, ld16);
    }
  };

  // ---- conv1: T0 = x (fp16 convert), cheb(128->256)+relu; epilogue writes T0 slot direct ----
  convert_cat_kernel<128><<<1250, 256, 0, stream>>>(x, Tcat);
  cheb(FDIM_IN, Wt, nullptr, bufA, 1, Tcat, 10 * DD1);

  // ---- conv2: cheb(256->256)+bias+relu -> bufB, bn1 (writes slot0 for conv3) ----
  cheb(DD1, Wt + 327680, convs_b, bufB, 1, nullptr, 0);
  bn(bufB, DD1, bn1_g, bn1_b, 0, Tcat, 10 * DD1);

  // ---- conv3 ----
  cheb(DD1, Wt + 327680 + 655360, convs_b + DD1, bufA, 1, nullptr, 0);
  bn(bufA, DD1, bn1_g, bn1_b, 0, Tcat, 10 * DD1);

  // ---- conv4 (bn writes h16 for fc1) ----
  cheb(DD1, Wt + 327680 + 2 * 655360, convs_b + 2 * DD1, bufB, 1, nullptr, 0);
  bn(bufB, DD1, bn1_g, bn1_b, 0, h16, DD1);

  // ---- fc1 (256->128) + bias, bn2+relu (writes h16b for fc2) ----
  mgemm(h16, DD1, Wtf1, DD1, 0, DD1, f1buf, DD2, DD2, fc1_b, 0, 0, nullptr, 0);
  bn(f1buf, DD2, bn2_g, bn2_b, 1, h16b, DD2);

  // ---- fc2 (128->64) + bias, bn3 ----
  mgemm(h16b, DD2, Wtf2, DD2, 0, DD2, f2buf, DD3, DD3, fc2_b, 0, 0, nullptr, 0);
  bn(f2buf, DD3, bn3_g, bn3_b, 0, nullptr, 0);

  // ---- fc3 (64->1) ----
  fc3_kernel<<<(N_NODES + 3) / 4, 256, 0, stream>>>(f2buf, fc3_w, fc3_b, out);
}